// Round 1
// 3054.525 us; speedup vs baseline: 1.1613x; 1.1613x over previous
//
#include <hip/hip_runtime.h>
#include <stdint.h>

// ---------------------------------------------------------------------------
// RNN speech decoder. R5:
//  * ALL input-gate weight matrices pre-transposed+packed to bf16 pair-words
//    [n][k/2] (word = pack(B[2k][n],B[2k+1][n])) by packB_kernel / daysel.
//    GEMM B-stage is now a pure 64B/thread coalesced copy (same as A-stage),
//    no fp32 strided loads, no pack VALU in the K-loop.
//  * L0 input GEMM fused fwd+bwd (N=3072): one dispatch, 768 blocks (3/CU)
//    instead of 2 x 384 -> double the latency hiding, one less serialization.
//  * scans: 1 barrier/step, parity-double-buffered hl, WARM=64 (unchanged).
// ---------------------------------------------------------------------------

#define T_SEQ 2048
#define G3    1536
#define GS    3072   // fused gate width (fwd | bwd)
#define HW    256    // packed bf16 words per h vector
#define CLEN  128
#define WARM  64
#define MAXST 192

typedef __attribute__((ext_vector_type(8))) short short8;
typedef __attribute__((ext_vector_type(4))) float f32x4;

__device__ inline unsigned int pack_bf16(float a, float b){
  unsigned int ua = __float_as_uint(a); ua = (ua + 0x7FFFu + ((ua>>16)&1u)) >> 16;
  unsigned int ub = __float_as_uint(b); ub = (ub + 0x7FFFu + ((ub>>16)&1u)) >> 16;
  return (ub<<16) | (ua & 0xFFFFu);
}
__device__ inline float bf2f(unsigned int h){ return __uint_as_float(h<<16); }

#define GBN 128
#define GBK 64
#define LSTR 36

// ---------------------------------------------------------------------------
// Day GEMM: C = softsign(x @ dayWT + bsel) -> bf16 hpadb rows 31..8222.
// fp32 A (lda=K=512); B pre-packed words [n][K/2]. BM=128, grid(64,4).
// ---------------------------------------------------------------------------
__global__ __launch_bounds__(256)
void day_gemm(const float* __restrict__ A, const unsigned int* __restrict__ Bpk,
              const float* __restrict__ bias, unsigned short* __restrict__ Cb)
{
  __shared__ __align__(16) unsigned int aL[128*LSTR];
  __shared__ __align__(16) unsigned int bL[GBN*LSTR];
  const int tid = threadIdx.x;
  const int m0 = blockIdx.x * 128;
  const int n0 = blockIdx.y * GBN;
  const int lane = tid & 63;
  const int w = tid >> 6;
  const int wm = (w & 1) * 64;
  const int wn = (w >> 1) * 64;
  const int ln = lane & 15;
  const int q  = lane >> 4;
  const int K = 512;

  f32x4 acc[4][4];
#pragma unroll
  for (int i=0;i<4;i++)
#pragma unroll
    for (int j=0;j<4;j++) acc[i][j] = (f32x4)0.f;

  const int ar = tid >> 1, ah = tid & 1;
  const int br = tid >> 1, bh = tid & 1;

  for (int kt = 0; kt < K/GBK; kt++){
    {
      const float* ap = A + (size_t)(m0+ar)*K + kt*GBK + ah*32;
      float4 av[8];
#pragma unroll
      for (int g=0; g<8; g++) av[g] = ((const float4*)ap)[g];
#pragma unroll
      for (int g=0; g<8; g++){
        aL[ar*LSTR + ah*16 + g*2    ] = pack_bf16(av[g].x, av[g].y);
        aL[ar*LSTR + ah*16 + g*2 + 1] = pack_bf16(av[g].z, av[g].w);
      }
    }
    {
      const unsigned int* bp = Bpk + (size_t)(n0+br)*(K>>1) + kt*32 + bh*16;
#pragma unroll
      for (int g=0; g<4; g++)
        *((uint4*)&bL[br*LSTR + bh*16 + g*4]) = ((const uint4*)bp)[g];
    }
    __syncthreads();
#pragma unroll
    for (int ks=0; ks<2; ks++){
      short8 af[4], bf[4];
#pragma unroll
      for (int i=0;i<4;i++){
        uint4 u = *(const uint4*)&aL[(wm + i*16 + ln)*LSTR + ks*16 + q*4];
        af[i] = *(const short8*)&u;
      }
#pragma unroll
      for (int j=0;j<4;j++){
        uint4 u = *(const uint4*)&bL[(wn + j*16 + ln)*LSTR + ks*16 + q*4];
        bf[j] = *(const short8*)&u;
      }
#pragma unroll
      for (int i=0;i<4;i++)
#pragma unroll
        for (int j=0;j<4;j++)
          acc[i][j] = __builtin_amdgcn_mfma_f32_16x16x32_bf16(af[i], bf[j], acc[i][j], 0,0,0);
    }
    __syncthreads();
  }
#pragma unroll
  for (int i=0;i<4;i++)
#pragma unroll
    for (int j=0;j<4;j++){
      int n = n0 + wn + j*16 + ln;
      float bs = bias[n];
#pragma unroll
      for (int r=0;r<4;r++){
        int m = m0 + wm + i*16 + q*4 + r;
        float v = acc[i][j][r] + bs;
        v = v / (1.f + fabsf(v));
        Cb[(size_t)(m+31)*512 + n] = (unsigned short)(pack_bf16(v, v) & 0xFFFFu);
      }
    }
}

// ---------------------------------------------------------------------------
// Input-gate GEMM, bf16 A. Template BM (64/128), AM: 1 = frame-gather from
// hpadb (bf16, 8223x512), 2 = packed-word concat from A1 (k<512) / A2.
// B: pre-packed pair-words [n][K/2], fused fwd|bwd over N=3072.
// C fp32 with ldc.
// ---------------------------------------------------------------------------
template<int BM, int AM>
__global__ __launch_bounds__(256)
void gemm_bt(const unsigned short* __restrict__ Abf,
             const unsigned int* __restrict__ A1, const unsigned int* __restrict__ A2,
             const unsigned int* __restrict__ Bpk,
             const float* __restrict__ biasF, const float* __restrict__ biasB,
             float* __restrict__ C, int K, int ldc)
{
  constexpr int AI = BM/32;
  __shared__ __align__(16) unsigned int aL[BM*LSTR];
  __shared__ __align__(16) unsigned int bL[GBN*LSTR];
  const int tid = threadIdx.x;
  const int m0 = blockIdx.x * BM;
  const int n0 = blockIdx.y * GBN;
  const int lane = tid & 63;
  const int w = tid >> 6;
  const int wm = (w & 1) * (BM/2);
  const int wn = (w >> 1) * 64;
  const int ln = lane & 15;
  const int q  = lane >> 4;

  f32x4 acc[AI][4];
#pragma unroll
  for (int i=0;i<AI;i++)
#pragma unroll
    for (int j=0;j<4;j++) acc[i][j] = (f32x4)0.f;

  const int ldKw = K >> 1;
  const int br = tid >> 1, bh = tid & 1;

  for (int kt = 0; kt < K/GBK; kt++){
    if (AM == 1){
      // BM=64: 4 threads/row, 32 B each
      const int ar = tid >> 2, ah = tid & 3;
      const int row = (m0+ar)*4 + (kt>>3);
      const uint4* ap = (const uint4*)(Abf + (size_t)row*512 + (kt&7)*64 + ah*16);
      *((uint4*)&aL[ar*LSTR + ah*8    ]) = ap[0];
      *((uint4*)&aL[ar*LSTR + ah*8 + 4]) = ap[1];
    } else {
      // BM=128: 2 threads/row, 64 B each, packed words
      const int ar = tid >> 1, ah = tid & 1;
      const int k0 = kt*GBK;
      const unsigned int* ub = ((k0 < 512) ? A1 : A2)
                               + (size_t)(m0+ar)*HW + ((k0 & 511) >> 1) + ah*16;
#pragma unroll
      for (int g=0; g<4; g++)
        *((uint4*)&aL[ar*LSTR + ah*16 + g*4]) = ((const uint4*)ub)[g];
    }
    {
      const unsigned int* bp = Bpk + (size_t)(n0+br)*ldKw + kt*32 + bh*16;
#pragma unroll
      for (int g=0; g<4; g++)
        *((uint4*)&bL[br*LSTR + bh*16 + g*4]) = ((const uint4*)bp)[g];
    }
    __syncthreads();
#pragma unroll
    for (int ks=0; ks<2; ks++){
      short8 af[AI], bf[4];
#pragma unroll
      for (int i=0;i<AI;i++){
        uint4 u = *(const uint4*)&aL[(wm + i*16 + ln)*LSTR + ks*16 + q*4];
        af[i] = *(const short8*)&u;
      }
#pragma unroll
      for (int j=0;j<4;j++){
        uint4 u = *(const uint4*)&bL[(wn + j*16 + ln)*LSTR + ks*16 + q*4];
        bf[j] = *(const short8*)&u;
      }
#pragma unroll
      for (int i=0;i<AI;i++)
#pragma unroll
        for (int j=0;j<4;j++)
          acc[i][j] = __builtin_amdgcn_mfma_f32_16x16x32_bf16(af[i], bf[j], acc[i][j], 0,0,0);
    }
    __syncthreads();
  }
#pragma unroll
  for (int i=0;i<AI;i++)
#pragma unroll
    for (int j=0;j<4;j++){
      int n = n0 + wn + j*16 + ln;
      float bs = (n < 1536) ? biasF[n] : biasB[n-1536];
#pragma unroll
      for (int r=0;r<4;r++){
        int m = m0 + wm + i*16 + q*4 + r;
        C[(size_t)m*ldc + n] = acc[i][j][r] + bs;
      }
    }
}

// ---------------------------------------------------------------------------
// Chunked GRU scan, single barrier/step (unchanged from R4).
// ---------------------------------------------------------------------------
__global__ __launch_bounds__(512, 2)
void scan_kernel(const float* __restrict__ gi,
                 const unsigned int* __restrict__ wpF, const unsigned int* __restrict__ wpB,
                 const float* __restrict__ bhnF, const float* __restrict__ bhnB,
                 unsigned int* __restrict__ hbF, unsigned int* __restrict__ hbB,
                 unsigned int* __restrict__ exch)
{
  const int bid = blockIdx.x;
  const int xcd = bid & 7;
  const int j   = (bid >> 3) & 7;
  const int sub = bid >> 6;
  const int group = xcd*4 + sub;
  const int dir   = group & 1;
  const int chunk = group >> 1;

  const float* gi_d = gi + dir*1536;
  const unsigned int* wp = dir ? wpB : wpF;
  const float* bhn = dir ? bhnB : bhnF;
  unsigned int* hb = dir ? hbB : hbF;
  unsigned int* ex = exch + (size_t)group * (MAXST*HW);

  const int tlo = chunk*CLEN, thi = chunk*CLEN + CLEN - 1;
  int ts, nst, tdelta;
  if (!dir){ int t0 = tlo - WARM; ts = t0 < 0 ? 0 : t0; nst = thi - ts + 1; tdelta = 1; }
  else     { int t0 = thi + WARM; ts = t0 > T_SEQ-1 ? T_SEQ-1 : t0; nst = ts - tlo + 1; tdelta = -1; }

  const int tid = threadIdx.x;
  const int g = tid >> 4;
  const int s = tid & 15;
  const bool isTail = (s == 0);

  // ---- 192 weights as float2[6][16]
  float2 wr[6][16];
#pragma unroll
  for (int m=0;m<6;m++){
    const uint4* p = (const uint4*)(wp + ((((size_t)(j*32+g)*6 + m)*16 + s) << 4));
#pragma unroll
    for (int t4=0;t4<4;t4++){
      uint4 d = p[t4];
      unsigned int dd[4] = {d.x, d.y, d.z, d.w};
#pragma unroll
      for (int e=0;e<4;e++)
        wr[m][t4*4+e] = make_float2(bf2f(dd[e] & 0xFFFFu),
                                    __uint_as_float(dd[e] & 0xFFFF0000u));
    }
  }

  __shared__ __align__(16) float hl[2][512];
  float2 bh2 = make_float2(0.f, 0.f);
  if (isTail) bh2 = *(const float2*)&bhn[j*64 + 2*g];
  float2 hp = make_float2(0.f, 0.f);
  hl[0][tid] = 0.f; hl[1][tid] = 0.f;
  __syncthreads();

  const unsigned int POISON = 0xAAAAAAAAu;
  const int pt = tid - 64;
  const bool isPoll = (tid >= 64 && tid < 320) && (pt < j*32 || pt >= j*32 + 32);

  int t = ts;
  for (int idx = 0; idx < nst; idx++){
    const int p = idx & 1;
    float2 gr, gz, gn;
    if (isTail){
      const float* gb = gi_d + (size_t)t*GS + j*64 + 2*g;
      gr = *(const float2*)(gb);
      gz = *(const float2*)(gb + 512);
      gn = *(const float2*)(gb + 1024);
    }
    if (idx > 0 && isPoll){
      const unsigned int* hpp = ex + (size_t)(idx-1)*HW + pt;
      unsigned int v;
      do { v = __hip_atomic_load(hpp, __ATOMIC_RELAXED, __HIP_MEMORY_SCOPE_AGENT); }
      while (v == POISON);
      hl[p][2*pt]   = bf2f(v & 0xFFFFu);
      hl[p][2*pt+1] = __uint_as_float(v & 0xFFFF0000u);
    }
    __syncthreads();                       // the only barrier

    const float2* h2 = (const float2*)hl[p];
    float2 ac0 = make_float2(0.f,0.f), ac1 = ac0, ac2 = ac0,
           ac3 = ac0, ac4 = ac0, ac5 = ac0;
#pragma unroll
    for (int jj=0;jj<16;jj++){
      float2 hh = h2[s + 16*jj];
      ac0.x += wr[0][jj].x*hh.x; ac0.y += wr[0][jj].y*hh.y;
      ac1.x += wr[1][jj].x*hh.x; ac1.y += wr[1][jj].y*hh.y;
      ac2.x += wr[2][jj].x*hh.x; ac2.y += wr[2][jj].y*hh.y;
      ac3.x += wr[3][jj].x*hh.x; ac3.y += wr[3][jj].y*hh.y;
      ac4.x += wr[4][jj].x*hh.x; ac4.y += wr[4][jj].y*hh.y;
      ac5.x += wr[5][jj].x*hh.x; ac5.y += wr[5][jj].y*hh.y;
    }
    float a0 = ac0.x+ac0.y, a1 = ac1.x+ac1.y, a2 = ac2.x+ac2.y,
          a3 = ac3.x+ac3.y, a4 = ac4.x+ac4.y, a5 = ac5.x+ac5.y;
#pragma unroll
    for (int off=1; off<16; off<<=1){
      a0 += __shfl_xor(a0, off, 64);
      a1 += __shfl_xor(a1, off, 64);
      a2 += __shfl_xor(a2, off, 64);
      a3 += __shfl_xor(a3, off, 64);
      a4 += __shfl_xor(a4, off, 64);
      a5 += __shfl_xor(a5, off, 64);
    }
    if (isTail){
      float r0 = __fdividef(1.f, 1.f + __expf(-(gr.x + a0)));
      float r1 = __fdividef(1.f, 1.f + __expf(-(gr.y + a1)));
      float z0 = __fdividef(1.f, 1.f + __expf(-(gz.x + a2)));
      float z1 = __fdividef(1.f, 1.f + __expf(-(gz.y + a3)));
      float e0 = __expf(2.f*(gn.x + r0*(a4 + bh2.x)));
      float e1 = __expf(2.f*(gn.y + r1*(a5 + bh2.y)));
      float n0 = 1.f - __fdividef(2.f, e0 + 1.f);
      float n1 = 1.f - __fdividef(2.f, e1 + 1.f);
      float h0 = (1.f - z0)*n0 + z0*hp.x;
      float h1 = (1.f - z1)*n1 + z1*hp.y;
      hp = make_float2(h0, h1);
      hl[p^1][j*64 + 2*g]     = h0;        // parity buffer: safe w/o barrier
      hl[p^1][j*64 + 2*g + 1] = h1;
      unsigned int bits = pack_bf16(h0, h1);
      if (bits == POISON) bits ^= 1u;
      __hip_atomic_store(ex + (size_t)idx*HW + j*32 + g, bits,
                         __ATOMIC_RELAXED, __HIP_MEMORY_SCOPE_AGENT);
      bool real = dir ? (t <= thi) : (t >= tlo);
      if (real) hb[(size_t)t*HW + j*32 + g] = bits;
    }
    t += tdelta;
  }
}

// ---------------------------------------------------------------------------
// Decoder: logits = [hf|hb](packed bf16) @ Wdec + bdec, row log_softmax.
// ---------------------------------------------------------------------------
__global__ __launch_bounds__(64)
void decoder_kernel(const unsigned int* __restrict__ hf, const unsigned int* __restrict__ hbk,
                    const float* __restrict__ Wd, const float* __restrict__ bd,
                    float* __restrict__ out)
{
  const int t = blockIdx.x;
  const int lane = threadIdx.x;
  __shared__ float y[1024];
  for (int i = lane; i < HW; i += 64){
    unsigned int uf = hf [(size_t)t*HW + i];
    unsigned int ub = hbk[(size_t)t*HW + i];
    y[2*i]       = bf2f(uf & 0xFFFFu); y[2*i+1]       = bf2f(uf >> 16);
    y[512 + 2*i] = bf2f(ub & 0xFFFFu); y[512 + 2*i+1] = bf2f(ub >> 16);
  }
  __syncthreads();
  float v = -1e30f;
  if (lane < 41){
    float acc = bd[lane];
    for (int k=0;k<1024;k++) acc += y[k] * Wd[(size_t)k*41 + lane];
    v = acc;
  }
  float m = v;
#pragma unroll
  for (int off=32; off; off>>=1) m = fmaxf(m, __shfl_xor(m, off, 64));
  float e = (lane < 41) ? __expf(v - m) : 0.f;
  float ssum = e;
#pragma unroll
  for (int off=32; off; off>>=1) ssum += __shfl_xor(ssum, off, 64);
  if (lane < 41) out[(size_t)t*41 + lane] = (v - m) - __logf(ssum);
}

// ---------------------------------------------------------------------------
// Prep kernels
// ---------------------------------------------------------------------------
__global__ void poison_kernel(unsigned int* p, long n){
  long i = (long)blockIdx.x*blockDim.x + threadIdx.x;
  long st = (long)gridDim.x*blockDim.x;
  for (; i < n; i += st) p[i] = 0xAAAAAAAAu;
}
__global__ void zero_u_kernel(unsigned int* p, int n){
  int i = blockIdx.x*blockDim.x + threadIdx.x;
  if (i < n) p[i] = 0u;
}
// day weights: packed word[n][k2] = pack(dayW[d][n][2k2], dayW[d][n][2k2+1])
// (B[k][n] = dayW[d][n][k] for C = x @ dayW^T). Fully coalesced both sides.
__global__ void daysel_kernel(const float* __restrict__ dw, const float* __restrict__ db,
                              const int* __restrict__ didx, unsigned int* __restrict__ wtpk,
                              float* __restrict__ bsel){
  int d = *didx;
  int i = blockIdx.x*256 + threadIdx.x;
  if (i < 512*256){
    int n = i >> 8, k2 = i & 255;
    const float* s = dw + (size_t)d*262144 + (size_t)n*512 + 2*k2;
    wtpk[i] = pack_bf16(s[0], s[1]);
  }
  if (i < 512) bsel[i] = db[(size_t)d*512 + i];
}
// Transpose-pack fp32 B [K][ldb] column slice -> pair-words dst[n][K/2]:
// dst[n*(K/2) + k2] = pack(B[2k2][n], B[2k2+1][n]).  64x64 LDS tile,
// coalesced loads (rows) and coalesced word writes (k2-runs of 32).
__global__ __launch_bounds__(256)
void packB_kernel(const float* __restrict__ src, int ldb,
                  unsigned int* __restrict__ dst, int K)
{
  __shared__ float tile[64][65];
  const int k0 = blockIdx.x * 64;
  const int n0 = blockIdx.y * 64;
  const int tid = threadIdx.x;
#pragma unroll
  for (int g=0; g<16; g++){
    int idx = g*256 + tid;              // 0..4095
    int kr = idx >> 6, nc = idx & 63;
    tile[kr][nc] = src[(size_t)(k0+kr)*ldb + n0 + nc];
  }
  __syncthreads();
  const int ldKw = K >> 1;
#pragma unroll
  for (int g=0; g<8; g++){
    int wi = g*256 + tid;               // 0..2047
    int nl = wi >> 5, k2 = wi & 31;
    dst[(size_t)(n0+nl)*ldKw + (k0>>1) + k2] = pack_bf16(tile[2*k2][nl], tile[2*k2+1][nl]);
  }
}
// Wh pack for scan layout (unchanged).
struct WhPtrs { const float* p[10]; };
__global__ void whpack_kernel(WhPtrs wps, unsigned int* __restrict__ dst){
  long i = (long)blockIdx.x*256 + threadIdx.x;
  if (i >= 10L*393216L) return;
  int ld  = (int)(i / 393216);
  int rem = (int)(i % 393216);
  int jj = rem & 15, s = (rem>>4)&15, X = rem >> 8;
  int m = X % 6, gj = X / 6;
  int g = gj & 31, j = gj >> 5;
  int C = (m>>1)*512 + j*64 + 2*g + (m&1);
  int r0 = 2*s + 32*jj;
  const float* W = wps.p[ld];
  dst[i] = pack_bf16(W[(size_t)r0*G3 + C], W[(size_t)(r0+1)*G3 + C]);
}

// ---------------------------------------------------------------------------
extern "C" void kernel_launch(void* const* d_in, const int* in_sizes, int n_in,
                              void* d_out, int out_size, void* d_ws, size_t ws_size,
                              hipStream_t stream)
{
  const float* x     = (const float*)d_in[0];
  const int*   didx  = (const int*)  d_in[1];
  const float* dayW  = (const float*)d_in[2];
  const float* dayB  = (const float*)d_in[3];
  const float* Wi0f  = (const float*)d_in[4];
  const float* bi0f  = (const float*)d_in[5];
  const float* Wh0f  = (const float*)d_in[6];
  const float* bhn0f = (const float*)d_in[7];
  const float* Wi0b  = (const float*)d_in[8];
  const float* bi0b  = (const float*)d_in[9];
  const float* Wh0b  = (const float*)d_in[10];
  const float* bhn0b = (const float*)d_in[11];
  const float* WiRf  = (const float*)d_in[12];
  const float* biRf  = (const float*)d_in[13];
  const float* WhRf  = (const float*)d_in[14];
  const float* bhnRf = (const float*)d_in[15];
  const float* WiRb  = (const float*)d_in[16];
  const float* biRb  = (const float*)d_in[17];
  const float* WhRb  = (const float*)d_in[18];
  const float* bhnRb = (const float*)d_in[19];
  const float* Wdec  = (const float*)d_in[20];
  const float* bdec  = (const float*)d_in[21];
  float* out = (float*)d_out;

  char* ws = (char*)d_ws;
  size_t off = 0;
  unsigned int* hbuf[5][2];
  for (int l=0;l<5;l++) for (int d=0;d<2;d++){
    hbuf[l][d] = (unsigned int*)(ws+off); off += (size_t)T_SEQ*HW*4;
  }
  float* gi   = (float*)(ws+off); off += (size_t)T_SEQ*GS*4;          // 25.2 MB
  unsigned short* hpadb = (unsigned short*)(ws+off); off += ((size_t)8223*512*2 + 255) & ~255ull;
  unsigned int* wtpk = (unsigned int*)(ws+off); off += (size_t)512*256*4;
  float* bsel = (float*)(ws+off); off += 2048;
  unsigned int* whp = (unsigned int*)(ws+off); off += (size_t)10*393216*4;
  unsigned int* exch = (unsigned int*)(ws+off); off += (size_t)32*MAXST*HW*4;
  unsigned int* bpk0 = (unsigned int*)(ws+off); off += (size_t)3072*8192*4;   // 100.7 MB
  unsigned int* bpkR = (unsigned int*)(ws+off); off += (size_t)4*3072*512*4;  // 25.2 MB
  // total ~203 MB

  const long EXN = (long)32*MAXST*HW;

  // --- prep
  hipLaunchKernelGGL(poison_kernel, dim3(1024), dim3(256), 0, stream, exch, EXN);
  hipLaunchKernelGGL(zero_u_kernel, dim3((7936+255)/256), dim3(256), 0, stream,
                     (unsigned int*)hpadb, 7936);  // rows 0..30 bf16 zeros
  hipLaunchKernelGGL(daysel_kernel, dim3(512), dim3(256), 0, stream,
                     dayW, dayB, didx, wtpk, bsel);
  WhPtrs wps;
  wps.p[0] = Wh0f; wps.p[1] = Wh0b;
  for (int l=0;l<4;l++){
    wps.p[2+2*l] = WhRf + (size_t)l*512*1536;
    wps.p[3+2*l] = WhRb + (size_t)l*512*1536;
  }
  hipLaunchKernelGGL(whpack_kernel, dim3((10*393216+255)/256), dim3(256), 0, stream,
                     wps, whp);

  // --- pre-pack input-gate weights to bf16 pair-words [n][K/2], fwd|bwd fused
  hipLaunchKernelGGL(packB_kernel, dim3(256,24), dim3(256), 0, stream,
                     Wi0f, G3, bpk0, 16384);
  hipLaunchKernelGGL(packB_kernel, dim3(256,24), dim3(256), 0, stream,
                     Wi0b, G3, bpk0 + (size_t)1536*8192, 16384);
  for (int l=0;l<4;l++){
    unsigned int* d = bpkR + (size_t)l*3072*512;
    hipLaunchKernelGGL(packB_kernel, dim3(16,24), dim3(256), 0, stream,
                       WiRf + (size_t)l*1024*1536, G3, d, 1024);
    hipLaunchKernelGGL(packB_kernel, dim3(16,24), dim3(256), 0, stream,
                       WiRb + (size_t)l*1024*1536, G3, d + (size_t)1536*512, 1024);
  }

  // --- day transform + softsign -> bf16 hpadb rows 31..8222
  hipLaunchKernelGGL(day_gemm, dim3(64,4), dim3(256), 0, stream,
                     x, wtpk, bsel, hpadb);

  // --- layer 0 input gates: fused fwd+bwd, frame-gather bf16 A, 768 blocks
  hipLaunchKernelGGL(HIP_KERNEL_NAME(gemm_bt<64,1>), dim3(32,24), dim3(256), 0, stream,
                     hpadb, (const unsigned int*)nullptr, (const unsigned int*)nullptr,
                     bpk0, bi0f, bi0b, gi, 16384, GS);
  hipLaunchKernelGGL(scan_kernel, dim3(256), dim3(512), 0, stream,
                     gi, whp, whp + 393216, bhn0f, bhn0b,
                     hbuf[0][0], hbuf[0][1], exch);

  // --- layers 1..4: fused fwd+bwd GEMM (N=3072), then scan
  for (int l=1;l<5;l++){
    hipLaunchKernelGGL(poison_kernel, dim3(1024), dim3(256), 0, stream, exch, EXN);
    hipLaunchKernelGGL(HIP_KERNEL_NAME(gemm_bt<128,2>), dim3(16,24), dim3(256), 0, stream,
                       (const unsigned short*)nullptr, hbuf[l-1][0], hbuf[l-1][1],
                       bpkR + (size_t)(l-1)*3072*512,
                       biRf + (l-1)*1536, biRb + (l-1)*1536, gi, 1024, GS);
    hipLaunchKernelGGL(scan_kernel, dim3(256), dim3(512), 0, stream,
                       gi, whp + (size_t)(2*l)*393216, whp + (size_t)(2*l+1)*393216,
                       bhnRf + (l-1)*512, bhnRb + (l-1)*512,
                       hbuf[l][0], hbuf[l][1], exch);
  }

  // --- decoder + log_softmax
  hipLaunchKernelGGL(decoder_kernel, dim3(2048), dim3(64), 0, stream,
                     hbuf[4][0], hbuf[4][1], Wdec, bdec, out);
}